// Round 1
// baseline (223.194 us; speedup 1.0000x reference)
//
#include <hip/hip_runtime.h>
#include <hip/hip_fp16.h>

#define EPS 0.1f
#define SINK_ITERS 50
#define KSCALE_LN 9.0109133472f   /* 13*ln2 : K scaled by 2^13 into f16 normal range */
#define USTRIDE 272               /* U row stride in halfs: 136 dwords == 8 (mod 32) -> 2/bank */

typedef _Float16 f16;
typedef _Float16 f16x4 __attribute__((ext_vector_type(4)));
typedef _Float16 f16x8 __attribute__((ext_vector_type(8)));
typedef float f32x4 __attribute__((ext_vector_type(4)));

#define PIN_U4(v) asm volatile("" : "+v"(v.x), "+v"(v.y), "+v"(v.z), "+v"(v.w))

__device__ __forceinline__ float wave_red_sum(float v) {
    #pragma unroll
    for (int o = 32; o; o >>= 1) v += __shfl_xor(v, o, 64);
    return v;
}

// ---------------- fused recon + row-normalize (outputs f16) ----------------
// blocks 0..511: recon partials; 512..767: xo rows -> xh; 768..1023: z rows -> zh.
__global__ __launch_bounds__(256) void k_pre(const float4* __restrict__ xo,
                                             const float4* __restrict__ xr,
                                             const float4* __restrict__ z,
                                             f16x4* __restrict__ xh,
                                             f16x4* __restrict__ zh,
                                             float* __restrict__ acc) {
    __shared__ float red[4];
    int b = blockIdx.x, t = threadIdx.x;
    if (b < 512) {
        int tid = b * 256 + t;
        float s = 0.f;
        for (int i = tid; i < 262144; i += 512 * 256) {
            float4 a = xo[i], r = xr[i];
            float d0 = r.x - a.x, d1 = r.y - a.y, d2 = r.z - a.z, d3 = r.w - a.w;
            s = fmaf(d0, d0, s); s = fmaf(d1, d1, s);
            s = fmaf(d2, d2, s); s = fmaf(d3, d3, s);
        }
        s = wave_red_sum(s);
        if ((t & 63) == 0) red[t >> 6] = s;
        __syncthreads();
        if (t == 0) atomicAdd(acc + 3, red[0] + red[1] + red[2] + red[3]);
    } else {
        int row = b - 512;
        const float4* src; f16x4* dst; int c4;
        if (row < 256) { src = xo + (size_t)row * 1024; dst = xh + (size_t)row * 1024; c4 = 1024; }
        else { src = z + (size_t)(row - 256) * 64; dst = zh + (size_t)(row - 256) * 64; c4 = 64; }
        float s = 0.f;
        for (int i = t; i < c4; i += 256) {
            float4 v = src[i];
            s = fmaf(v.x, v.x, s); s = fmaf(v.y, v.y, s);
            s = fmaf(v.z, v.z, s); s = fmaf(v.w, v.w, s);
        }
        s = wave_red_sum(s);
        if ((t & 63) == 0) red[t >> 6] = s;
        __syncthreads();
        float tot = red[0] + red[1] + red[2] + red[3];
        float rn = 1.f / sqrtf(fmaxf(tot, 1e-8f));
        for (int i = t; i < c4; i += 256) {
            float4 v = src[i];
            f16x4 h;
            h[0] = (f16)(v.x * rn); h[1] = (f16)(v.y * rn);
            h[2] = (f16)(v.z * rn); h[3] = (f16)(v.w * rn);
            dst[i] = h;
        }
    }
}

// ---------------- f16 MFMA GEMM: X@X^T k-slabs, xh (zb<16) and zh (zb>=16) ----------------
// grid (4,4,20), block 256 (4 waves). 64x64 tile; wave wv does 16-row strip x 64 cols.
__global__ __launch_bounds__(256) void k_gemm_f16(const uint4* __restrict__ xh,
                                                  const uint4* __restrict__ zh,
                                                  float* __restrict__ part,
                                                  float* __restrict__ part2) {
    __shared__ __align__(16) f16 Ai[64 * 40], Bj[64 * 40];
    int zb = blockIdx.z;
    const uint4* X; int lda8, k0, nchunk; float* out;
    if (zb < 16) { X = xh; lda8 = 512; k0 = zb * 256; nchunk = 8; out = part + (size_t)zb * 65536; }
    else { X = zh; lda8 = 32; k0 = (zb - 16) * 64; nchunk = 2; out = part2 + (size_t)(zb - 16) * 65536; }
    int i0 = blockIdx.x * 64, j0 = blockIdx.y * 64;
    int t = threadIdx.x, lane = t & 63, wv = t >> 6;
    int m16 = lane & 15, quad = lane >> 4;
    int r = t >> 2, ko = (t & 3) * 8;
    f32x4 acc[4] = {};
    for (int ch = 0; ch < nchunk; ch++) {
        int kb8 = (k0 + ch * 32) >> 3;
        uint4 va = X[(size_t)(i0 + r) * lda8 + kb8 + (t & 3)];
        uint4 vb = X[(size_t)(j0 + r) * lda8 + kb8 + (t & 3)];
        __syncthreads();
        *(uint4*)&Ai[r * 40 + ko] = va;
        *(uint4*)&Bj[r * 40 + ko] = vb;
        __syncthreads();
        f16x8 a = *(const f16x8*)&Ai[(wv * 16 + m16) * 40 + quad * 8];
        #pragma unroll
        for (int st = 0; st < 4; st++) {
            f16x8 bfr = *(const f16x8*)&Bj[(st * 16 + m16) * 40 + quad * 8];
            acc[st] = __builtin_amdgcn_mfma_f32_16x16x32_f16(a, bfr, acc[st], 0, 0, 0);
        }
    }
    #pragma unroll
    for (int st = 0; st < 4; st++)
        #pragma unroll
        for (int reg = 0; reg < 4; reg++)
            out[(i0 + wv * 16 + quad * 4 + reg) * 256 + j0 + st * 16 + m16] = acc[st][reg];
}

// ---------------- Do = clip(1 - sum of 16 slabs, 0) ----------------
__global__ __launch_bounds__(256) void k_reduce_do(const float* __restrict__ part,
                                                   float* __restrict__ Do) {
    int e = blockIdx.x * 256 + threadIdx.x;
    float s = 0.f;
    for (int sl = 0; sl < 16; sl++) s += part[(size_t)sl * 65536 + e];
    Do[e] = fmaxf(1.f - s, 0.f);
}

// ---------------- exact median of 65536 non-negative floats ----------------
__device__ __forceinline__ int med_bin(float v) {
    int b = (int)(v * 4096.f);
    if (v < (float)b * (1.f / 4096.f)) b--;
    else if (v >= (float)(b + 1) * (1.f / 4096.f)) b++;
    if (b < 0) b = 0;
    if (b > 8191) b = 8191;
    return b;
}

__global__ __launch_bounds__(1024) void k_median(const float* __restrict__ D,
                                                 float* __restrict__ out_sigma) {
    __shared__ int hist[8192];
    __shared__ int redc[16];
    __shared__ int sh_bin[2];
    __shared__ int sh_tot;
    int t = threadIdx.x;
    unsigned r[64];
    #pragma unroll
    for (int i = 0; i < 64; i++) r[i] = __float_as_uint(D[t + i * 1024]);
    #pragma unroll
    for (int j = 0; j < 8; j++) hist[t + j * 1024] = 0;
    __syncthreads();
    #pragma unroll
    for (int i = 0; i < 64; i++)
        atomicAdd(&hist[med_bin(__uint_as_float(r[i]))], 1);
    __syncthreads();
    int s8 = 0;
    #pragma unroll
    for (int j = 0; j < 8; j++) s8 += hist[t * 8 + j];
    int inc = s8;
    #pragma unroll
    for (int o = 1; o < 64; o <<= 1) {
        int vv = __shfl_up(inc, o, 64);
        if ((t & 63) >= o) inc += vv;
    }
    if ((t & 63) == 63) redc[t >> 6] = inc;
    __syncthreads();
    int woff = 0;
    for (int wv = 0; wv < (t >> 6); wv++) woff += redc[wv];
    int excl = woff + inc - s8;
    for (int sel = 0; sel < 2; sel++) {
        int k = 32767 + sel;
        if (excl <= k && k < excl + s8) {
            int cum = excl, bfound = 8191;
            bool found = false;
            for (int j = 0; j < 8; j++) {
                int hc = hist[t * 8 + j];
                if (!found) {
                    if (cum + hc > k) { bfound = t * 8 + j; found = true; }
                    else cum += hc;
                }
            }
            sh_bin[sel] = bfound;
        }
    }
    __syncthreads();
    unsigned res[2];
    for (int sel = 0; sel < 2; sel++) {
        int k = 32767 + sel;
        int b = sh_bin[sel];
        unsigned lo = __float_as_uint((float)b * (1.f / 4096.f));
        unsigned hi = __float_as_uint((float)(b + 1) * (1.f / 4096.f));
        while (hi - lo > 1u) {
            unsigned mid = (lo + hi) >> 1;
            int c = 0;
            #pragma unroll
            for (int i = 0; i < 64; i++) c += (r[i] < mid) ? 1 : 0;
            #pragma unroll
            for (int o = 32; o; o >>= 1) c += __shfl_xor(c, o, 64);
            if ((t & 63) == 0) redc[t >> 6] = c;
            __syncthreads();
            if (t == 0) {
                int tot = 0;
                for (int wv = 0; wv < 16; wv++) tot += redc[wv];
                sh_tot = tot;
            }
            __syncthreads();
            if (sh_tot <= k) lo = mid; else hi = mid;
        }
        res[sel] = lo;
    }
    if (t == 0)
        out_sigma[0] = 0.5f * (__uint_as_float(res[0]) + __uint_as_float(res[1]));
}

// ---------------- prep: S, P, EPS*logP, f16 kernel K; Dl summed inline from part2 ----------------
__global__ __launch_bounds__(256) void k_prep(const float* __restrict__ Do,
                                              const float* __restrict__ part2,
                                              const float* __restrict__ wsacc,
                                              const float* __restrict__ lsl,
                                              float* __restrict__ Po, float* __restrict__ Pl,
                                              float* __restrict__ ELo, float* __restrict__ ELl,
                                              f16* __restrict__ Kh) {
    __shared__ float red[8];
    int i = blockIdx.x, j = threadIdx.x;
    int e = i * 256 + j;
    float sig_o = wsacc[4];
    if (sig_o == 0.f) sig_o = 1e-6f;
    float x = lsl[0];
    float sp = (x > 20.f) ? x : log1pf(__expf(x));
    float sig_l = sp + 1e-6f;
    float i2o = 1.f / (2.f * sig_o * sig_o);
    float i2l = 1.f / (2.f * sig_l * sig_l);
    float d_o = Do[e];
    float sD = part2[e] + part2[65536 + e] + part2[131072 + e] + part2[196608 + e];
    float d_l = fmaxf(1.f - sD, 0.f);
    float so = (i == j) ? 0.f : __expf(-d_o * d_o * i2o);
    float sl = (i == j) ? 0.f : __expf(-d_l * d_l * i2l);
    float wso = wave_red_sum(so);
    float wsl = wave_red_sum(sl);
    if ((j & 63) == 0) { red[j >> 6] = wso; red[4 + (j >> 6)] = wsl; }
    __syncthreads();
    float sum_o = red[0] + red[1] + red[2] + red[3];
    float sum_l = red[4] + red[5] + red[6] + red[7];
    float po = so / fmaxf(sum_o, 1e-8f);
    float pl = sl / fmaxf(sum_l, 1e-8f);
    Po[e] = po;
    Pl[e] = pl;
    ELo[e] = EPS * __logf(fmaxf(po, 1e-8f));
    ELl[e] = EPS * __logf(fmaxf(pl, 1e-8f));
    // K'[k=i][c=j] = exp(-C/eps) * 2^13; half index = ((k>>3)*256 + c)*8 + (k&7)
    float kv = __expf(-d_o * (1.f / EPS) + KSCALE_LN);
    Kh[(((i >> 3) * 256 + j) << 3) + (i & 7)] = (f16)kv;
}

// ---------------- Sinkhorn via MFMA: 192 WGs x 512 thr, 4 problems per WG ----------------
// M-tile underfilled on purpose (rows 0..3 valid): WG count = 768/4 covers 192 CUs.
// U rows replicated on read via (m16&3) -> 4-lane broadcast; USTRIDE=272 halfs
// (136 dw == 8 mod 32) -> exactly 2 distinct dwords/bank per b128 read (free).
// Epilogue (log/exp/writes) only on quad-0 lanes (C/D rows 0..3).
__global__ __launch_bounds__(512, 2) void k_sinkhorn(const float* __restrict__ Po,
                                                     const float* __restrict__ Pl,
                                                     const float* __restrict__ ELo,
                                                     const float* __restrict__ ELl,
                                                     const uint4* __restrict__ Kq,
                                                     float* __restrict__ wsacc) {
    __shared__ __align__(16) f16 U[2][4 * USTRIDE];
    __shared__ float CW[8][4];
    int t = threadIdx.x;
    int lane = t & 63, wv = t >> 6;
    int m16 = lane & 15, quad = lane >> 4;
    int w = blockIdx.x;           // 192 WGs
    int s = w >> 6;               // sinkhorn instance 0..2
    int ibase = (w & 63) * 4;     // 4 problems per WG

    // B-fragments: K[k=kc*32+quad*8+j][c], register-resident
    uint4 bf0[8], bf1[8];
    int cA = 32 * wv + m16, cB = cA + 16;
    #pragma unroll
    for (int kc = 0; kc < 8; kc++) {
        bf0[kc] = Kq[(kc * 4 + quad) * 256 + cA];
        bf1[kc] = Kq[(kc * 4 + quad) * 256 + cB];
    }
    #pragma unroll
    for (int kc = 0; kc < 8; kc++) { PIN_U4(bf0[kc]); PIN_U4(bf1[kc]); }

    // EL constants only where outputs live (quad 0, rows 0..3)
    const float* ELa_b = (s == 1 ? ELl : ELo);
    const float* ELb_b = (s == 2 ? ELo : ELl);
    float ela[2][4] = {}, elb[2][4] = {};
    if (quad == 0) {
        #pragma unroll
        for (int reg = 0; reg < 4; reg++) {
            int i = ibase + reg;
            ela[0][reg] = ELa_b[i * 256 + cA] + EPS * KSCALE_LN;
            ela[1][reg] = ELa_b[i * 256 + cB] + EPS * KSCALE_LN;
            elb[0][reg] = ELb_b[i * 256 + cA] + EPS * KSCALE_LN;
            elb[1][reg] = ELb_b[i * 256 + cB] + EPS * KSCALE_LN;
        }
    }

    // init U[0] = 1.0 (f16 0x3C00): 4*272 halfs = 136 uint4
    if (t < 136)
        *(uint4*)&U[0][t * 8] =
            make_uint4(0x3C003C00u, 0x3C003C00u, 0x3C003C00u, 0x3C003C00u);
    __syncthreads();

    float df[2][4] = {}, dg[2][4] = {};
    for (int it = 0; it < 2 * SINK_ITERS; it++) {
        const f16* ub = &U[it & 1][0];
        f16* un = &U[(it + 1) & 1][0];
        f32x4 acc0 = {0.f, 0.f, 0.f, 0.f}, acc1 = {0.f, 0.f, 0.f, 0.f};
        #pragma unroll
        for (int kc = 0; kc < 8; kc++) {
            f16x8 a = *(const f16x8*)&ub[(m16 & 3) * USTRIDE + kc * 32 + quad * 8];
            acc0 = __builtin_amdgcn_mfma_f32_16x16x32_f16(a, __builtin_bit_cast(f16x8, bf0[kc]),
                                                          acc0, 0, 0, 0);
            acc1 = __builtin_amdgcn_mfma_f32_16x16x32_f16(a, __builtin_bit_cast(f16x8, bf1[kc]),
                                                          acc1, 0, 0, 0);
        }
        bool fstep = (it & 1);
        if (quad == 0) {
            #pragma unroll
            for (int reg = 0; reg < 4; reg++) {
                float z0 = acc0[reg], z1 = acc1[reg];
                float e0 = fstep ? ela[0][reg] : elb[0][reg];
                float e1 = fstep ? ela[1][reg] : elb[1][reg];
                float d0 = e0 - EPS * __logf(z0);
                float d1 = e1 - EPS * __logf(z1);
                if (fstep) { df[0][reg] = d0; df[1][reg] = d1; }
                else       { dg[0][reg] = d0; dg[1][reg] = d1; }
                un[reg * USTRIDE + cA] = (f16)__expf(d0);
                un[reg * USTRIDE + cB] = (f16)__expf(d1);
            }
        }
        __syncthreads();
    }

    // cost epilogue: problem r=ibase+reg: sum_c Pa[c]*f[c] + Pb[c]*g[c]
    const float* PaB = (s == 1 ? Pl : Po);
    const float* PbB = (s == 2 ? Po : Pl);
    float cs[4] = {};
    if (quad == 0) {
        #pragma unroll
        for (int reg = 0; reg < 4; reg++) {
            int i = ibase + reg;
            cs[reg] = PaB[i * 256 + cA] * df[0][reg] + PbB[i * 256 + cA] * dg[0][reg] +
                      PaB[i * 256 + cB] * df[1][reg] + PbB[i * 256 + cB] * dg[1][reg];
        }
    }
    #pragma unroll
    for (int o = 1; o < 16; o <<= 1) {
        #pragma unroll
        for (int reg = 0; reg < 4; reg++) cs[reg] += __shfl_xor(cs[reg], o, 64);
    }
    if (lane == 0) {
        #pragma unroll
        for (int reg = 0; reg < 4; reg++) CW[wv][reg] = cs[reg];
    }
    __syncthreads();
    if (t == 0) {
        float v = 0.f;
        for (int w2 = 0; w2 < 8; w2++)
            v += CW[w2][0] + CW[w2][1] + CW[w2][2] + CW[w2][3];
        atomicAdd(&wsacc[s], v);
    }
}

// ---------------- finalize ----------------
__global__ void k_final(const float* __restrict__ wsacc, const float* __restrict__ lvr_p,
                        const float* __restrict__ lvt_p, float* __restrict__ out) {
    float recon = wsacc[3] * (1.f / (256.f * 4096.f));
    float ot0 = wsacc[0] * (1.f / 256.f);
    float ot1 = wsacc[1] * (1.f / 256.f);
    float ot2 = wsacc[2] * (1.f / 256.f);
    float topo = ot0 - 0.5f * ot1 - 0.5f * ot2;
    topo = topo > 0.f ? topo : 0.f;  // * TOPO_MULT (=1)
    float lvr = lvr_p[0], lvt = lvt_p[0];
    out[0] = 0.5f * __expf(-lvr) * recon + 0.5f * lvr +
             0.5f * __expf(-lvt) * topo + 0.5f * lvt;
    out[1] = recon;
    out[2] = topo;
}

extern "C" void kernel_launch(void* const* d_in, const int* in_sizes, int n_in,
                              void* d_out, int out_size, void* d_ws, size_t ws_size,
                              hipStream_t stream) {
    const float* xo = (const float*)d_in[0];
    const float* xr = (const float*)d_in[1];
    const float* z  = (const float*)d_in[2];
    const float* lsl = (const float*)d_in[3];
    const float* lvr = (const float*)d_in[4];
    const float* lvt = (const float*)d_in[5];
    float* out = (float*)d_out;
    float* ws = (float*)d_ws;

    // ws layout (floats)
    float* acc = ws;                    // [0..2] ot sums, [3] recon sum, [4] sigma_orig
    float* xh  = ws + 64;               // 256*4096 f16 = 524288 floats
    float* zh  = xh + 524288;           // 256*256 f16 = 32768 floats
    float* Do  = zh + 32768;
    float* Po  = Do + 65536;
    float* Pl  = Po + 65536;
    float* ELo = Pl + 65536;
    float* ELl = ELo + 65536;
    float* Kh  = ELl + 65536;           // 65536 f16 = 32768 floats
    float* part = Kh + 32768;           // 16*65536 (xh-gemm slabs)
    float* part2 = Po;                  // 4*65536 overlay: consumed by prep before it writes Po..ELl

    hipMemsetAsync(acc, 0, 64, stream);
    k_pre<<<1024, 256, 0, stream>>>((const float4*)xo, (const float4*)xr, (const float4*)z,
                                    (f16x4*)xh, (f16x4*)zh, acc);
    k_gemm_f16<<<dim3(4, 4, 20), 256, 0, stream>>>((const uint4*)xh, (const uint4*)zh,
                                                   part, part2);
    k_reduce_do<<<256, 256, 0, stream>>>(part, Do);
    k_median<<<1, 1024, 0, stream>>>(Do, acc + 4);
    k_prep<<<256, 256, 0, stream>>>(Do, part2, acc, lsl, Po, Pl, ELo, ELl, (f16*)Kh);
    k_sinkhorn<<<192, 512, 0, stream>>>(Po, Pl, ELo, ELl, (const uint4*)Kh, acc);
    k_final<<<1, 1, 0, stream>>>(acc, lvr, lvt, out);
}

// Round 3
// 206.269 us; speedup vs baseline: 1.0821x; 1.0821x over previous
//
#include <hip/hip_runtime.h>
#include <hip/hip_fp16.h>

#define EPS 0.1f
#define SINK_ITERS 50
#define KSCALE_LN 9.0109133472f   /* 13*ln2 : K scaled by 2^13 into f16 normal range */
#define USTRIDE 272               /* U row stride in halfs: 136 dwords == 8 (mod 32) -> 2/bank */

typedef _Float16 f16;
typedef _Float16 f16x4 __attribute__((ext_vector_type(4)));
typedef _Float16 f16x8 __attribute__((ext_vector_type(8)));
typedef float f32x4 __attribute__((ext_vector_type(4)));

#define PIN_U4(v) asm volatile("" : "+v"(v.x), "+v"(v.y), "+v"(v.z), "+v"(v.w))

__device__ __forceinline__ float wave_red_sum(float v) {
    #pragma unroll
    for (int o = 32; o; o >>= 1) v += __shfl_xor(v, o, 64);
    return v;
}

// 1-of-4 select by 2-bit lane value q (2-stage cndmask, no dynamic indexing)
__device__ __forceinline__ float sel4(int q, float a, float b, float c, float d) {
    float ab = (q & 1) ? b : a;
    float cd = (q & 1) ? d : c;
    return (q & 2) ? cd : ab;
}

// ---------------- fused recon + row-normalize (outputs f16) ----------------
// blocks 0..511: recon partials; 512..767: xo rows -> xh; 768..1023: z rows -> zh.
__global__ __launch_bounds__(256) void k_pre(const float4* __restrict__ xo,
                                             const float4* __restrict__ xr,
                                             const float4* __restrict__ z,
                                             f16x4* __restrict__ xh,
                                             f16x4* __restrict__ zh,
                                             float* __restrict__ acc) {
    __shared__ float red[4];
    int b = blockIdx.x, t = threadIdx.x;
    if (b < 512) {
        int tid = b * 256 + t;
        float s = 0.f;
        for (int i = tid; i < 262144; i += 512 * 256) {
            float4 a = xo[i], r = xr[i];
            float d0 = r.x - a.x, d1 = r.y - a.y, d2 = r.z - a.z, d3 = r.w - a.w;
            s = fmaf(d0, d0, s); s = fmaf(d1, d1, s);
            s = fmaf(d2, d2, s); s = fmaf(d3, d3, s);
        }
        s = wave_red_sum(s);
        if ((t & 63) == 0) red[t >> 6] = s;
        __syncthreads();
        if (t == 0) atomicAdd(acc + 3, red[0] + red[1] + red[2] + red[3]);
    } else {
        int row = b - 512;
        const float4* src; f16x4* dst; int c4;
        if (row < 256) { src = xo + (size_t)row * 1024; dst = xh + (size_t)row * 1024; c4 = 1024; }
        else { src = z + (size_t)(row - 256) * 64; dst = zh + (size_t)(row - 256) * 64; c4 = 64; }
        float s = 0.f;
        for (int i = t; i < c4; i += 256) {
            float4 v = src[i];
            s = fmaf(v.x, v.x, s); s = fmaf(v.y, v.y, s);
            s = fmaf(v.z, v.z, s); s = fmaf(v.w, v.w, s);
        }
        s = wave_red_sum(s);
        if ((t & 63) == 0) red[t >> 6] = s;
        __syncthreads();
        float tot = red[0] + red[1] + red[2] + red[3];
        float rn = 1.f / sqrtf(fmaxf(tot, 1e-8f));
        for (int i = t; i < c4; i += 256) {
            float4 v = src[i];
            f16x4 h;
            h[0] = (f16)(v.x * rn); h[1] = (f16)(v.y * rn);
            h[2] = (f16)(v.z * rn); h[3] = (f16)(v.w * rn);
            dst[i] = h;
        }
    }
}

// ---------------- f16 MFMA GEMM: X@X^T k-slabs, xh (zb<16) and zh (zb>=16) ----------------
// grid (4,4,20), block 256 (4 waves). 64x64 tile; wave wv does 16-row strip x 64 cols.
__global__ __launch_bounds__(256) void k_gemm_f16(const uint4* __restrict__ xh,
                                                  const uint4* __restrict__ zh,
                                                  float* __restrict__ part,
                                                  float* __restrict__ part2) {
    __shared__ __align__(16) f16 Ai[64 * 40], Bj[64 * 40];
    int zb = blockIdx.z;
    const uint4* X; int lda8, k0, nchunk; float* out;
    if (zb < 16) { X = xh; lda8 = 512; k0 = zb * 256; nchunk = 8; out = part + (size_t)zb * 65536; }
    else { X = zh; lda8 = 32; k0 = (zb - 16) * 64; nchunk = 2; out = part2 + (size_t)(zb - 16) * 65536; }
    int i0 = blockIdx.x * 64, j0 = blockIdx.y * 64;
    int t = threadIdx.x, lane = t & 63, wv = t >> 6;
    int m16 = lane & 15, quad = lane >> 4;
    int r = t >> 2, ko = (t & 3) * 8;
    f32x4 acc[4] = {};
    for (int ch = 0; ch < nchunk; ch++) {
        int kb8 = (k0 + ch * 32) >> 3;
        uint4 va = X[(size_t)(i0 + r) * lda8 + kb8 + (t & 3)];
        uint4 vb = X[(size_t)(j0 + r) * lda8 + kb8 + (t & 3)];
        __syncthreads();
        *(uint4*)&Ai[r * 40 + ko] = va;
        *(uint4*)&Bj[r * 40 + ko] = vb;
        __syncthreads();
        f16x8 a = *(const f16x8*)&Ai[(wv * 16 + m16) * 40 + quad * 8];
        #pragma unroll
        for (int st = 0; st < 4; st++) {
            f16x8 bfr = *(const f16x8*)&Bj[(st * 16 + m16) * 40 + quad * 8];
            acc[st] = __builtin_amdgcn_mfma_f32_16x16x32_f16(a, bfr, acc[st], 0, 0, 0);
        }
    }
    #pragma unroll
    for (int st = 0; st < 4; st++)
        #pragma unroll
        for (int reg = 0; reg < 4; reg++)
            out[(i0 + wv * 16 + quad * 4 + reg) * 256 + j0 + st * 16 + m16] = acc[st][reg];
}

// ---------------- Do = clip(1 - sum of 16 slabs, 0) ----------------
__global__ __launch_bounds__(256) void k_reduce_do(const float* __restrict__ part,
                                                   float* __restrict__ Do) {
    int e = blockIdx.x * 256 + threadIdx.x;
    float s = 0.f;
    for (int sl = 0; sl < 16; sl++) s += part[(size_t)sl * 65536 + e];
    Do[e] = fmaxf(1.f - s, 0.f);
}

// ---------------- exact median of 65536 non-negative floats ----------------
__device__ __forceinline__ int med_bin(float v) {
    int b = (int)(v * 4096.f);
    if (v < (float)b * (1.f / 4096.f)) b--;
    else if (v >= (float)(b + 1) * (1.f / 4096.f)) b++;
    if (b < 0) b = 0;
    if (b > 8191) b = 8191;
    return b;
}

__global__ __launch_bounds__(1024) void k_median(const float* __restrict__ D,
                                                 float* __restrict__ out_sigma) {
    __shared__ int hist[8192];
    __shared__ int redc[16];
    __shared__ int sh_bin[2];
    __shared__ int sh_tot;
    int t = threadIdx.x;
    unsigned r[64];
    #pragma unroll
    for (int i = 0; i < 64; i++) r[i] = __float_as_uint(D[t + i * 1024]);
    #pragma unroll
    for (int j = 0; j < 8; j++) hist[t + j * 1024] = 0;
    __syncthreads();
    #pragma unroll
    for (int i = 0; i < 64; i++)
        atomicAdd(&hist[med_bin(__uint_as_float(r[i]))], 1);
    __syncthreads();
    int s8 = 0;
    #pragma unroll
    for (int j = 0; j < 8; j++) s8 += hist[t * 8 + j];
    int inc = s8;
    #pragma unroll
    for (int o = 1; o < 64; o <<= 1) {
        int vv = __shfl_up(inc, o, 64);
        if ((t & 63) >= o) inc += vv;
    }
    if ((t & 63) == 63) redc[t >> 6] = inc;
    __syncthreads();
    int woff = 0;
    for (int wv = 0; wv < (t >> 6); wv++) woff += redc[wv];
    int excl = woff + inc - s8;
    for (int sel = 0; sel < 2; sel++) {
        int k = 32767 + sel;
        if (excl <= k && k < excl + s8) {
            int cum = excl, bfound = 8191;
            bool found = false;
            for (int j = 0; j < 8; j++) {
                int hc = hist[t * 8 + j];
                if (!found) {
                    if (cum + hc > k) { bfound = t * 8 + j; found = true; }
                    else cum += hc;
                }
            }
            sh_bin[sel] = bfound;
        }
    }
    __syncthreads();
    unsigned res[2];
    for (int sel = 0; sel < 2; sel++) {
        int k = 32767 + sel;
        int b = sh_bin[sel];
        unsigned lo = __float_as_uint((float)b * (1.f / 4096.f));
        unsigned hi = __float_as_uint((float)(b + 1) * (1.f / 4096.f));
        while (hi - lo > 1u) {
            unsigned mid = (lo + hi) >> 1;
            int c = 0;
            #pragma unroll
            for (int i = 0; i < 64; i++) c += (r[i] < mid) ? 1 : 0;
            #pragma unroll
            for (int o = 32; o; o >>= 1) c += __shfl_xor(c, o, 64);
            if ((t & 63) == 0) redc[t >> 6] = c;
            __syncthreads();
            if (t == 0) {
                int tot = 0;
                for (int wv = 0; wv < 16; wv++) tot += redc[wv];
                sh_tot = tot;
            }
            __syncthreads();
            if (sh_tot <= k) lo = mid; else hi = mid;
        }
        res[sel] = lo;
    }
    if (t == 0)
        out_sigma[0] = 0.5f * (__uint_as_float(res[0]) + __uint_as_float(res[1]));
}

// ---------------- prep: S, P, EPS*logP, f16 kernel K; Dl summed inline from part2 ----------------
__global__ __launch_bounds__(256) void k_prep(const float* __restrict__ Do,
                                              const float* __restrict__ part2,
                                              const float* __restrict__ wsacc,
                                              const float* __restrict__ lsl,
                                              float* __restrict__ Po, float* __restrict__ Pl,
                                              float* __restrict__ ELo, float* __restrict__ ELl,
                                              f16* __restrict__ Kh) {
    __shared__ float red[8];
    int i = blockIdx.x, j = threadIdx.x;
    int e = i * 256 + j;
    float sig_o = wsacc[4];
    if (sig_o == 0.f) sig_o = 1e-6f;
    float x = lsl[0];
    float sp = (x > 20.f) ? x : log1pf(__expf(x));
    float sig_l = sp + 1e-6f;
    float i2o = 1.f / (2.f * sig_o * sig_o);
    float i2l = 1.f / (2.f * sig_l * sig_l);
    float d_o = Do[e];
    float sD = part2[e] + part2[65536 + e] + part2[131072 + e] + part2[196608 + e];
    float d_l = fmaxf(1.f - sD, 0.f);
    float so = (i == j) ? 0.f : __expf(-d_o * d_o * i2o);
    float sl = (i == j) ? 0.f : __expf(-d_l * d_l * i2l);
    float wso = wave_red_sum(so);
    float wsl = wave_red_sum(sl);
    if ((j & 63) == 0) { red[j >> 6] = wso; red[4 + (j >> 6)] = wsl; }
    __syncthreads();
    float sum_o = red[0] + red[1] + red[2] + red[3];
    float sum_l = red[4] + red[5] + red[6] + red[7];
    float po = so / fmaxf(sum_o, 1e-8f);
    float pl = sl / fmaxf(sum_l, 1e-8f);
    Po[e] = po;
    Pl[e] = pl;
    ELo[e] = EPS * __logf(fmaxf(po, 1e-8f));
    ELl[e] = EPS * __logf(fmaxf(pl, 1e-8f));
    // K'[k=i][c=j] = exp(-C/eps) * 2^13; half index = ((k>>3)*256 + c)*8 + (k&7)
    float kv = __expf(-d_o * (1.f / EPS) + KSCALE_LN);
    Kh[(((i >> 3) * 256 + j) << 3) + (i & 7)] = (f16)kv;
}

// ---------------- Sinkhorn via MFMA: 192 WGs x 256 thr (4 waves), 4 problems per WG ----------------
// Each wave owns 64 columns (4 col-tiles x 8 k-chunks of K register-resident: bf[4][8]).
// 1 wave/SIMD at 192 WGs: full VGPR budget usable, no intra-SIMD issue serialization.
// Split accumulators (K-halves) shorten MFMA dep chains to 4-deep x 8 interleaved.
// C rows are 4x quad-duplicated (A rows replicated mod 4) -> quad q epilogues col-tile q
// via 2-stage cndmask select; all 64 lanes write one distinct column each.
// Per-iter update: un = E * exp(-EPS*log z) with E = exp(el) hoisted; log-domain d
// recomputed after the loop from z of iterations 198 (last g) / 199 (last f).
__global__ __launch_bounds__(256, 1) void k_sinkhorn(const float* __restrict__ Po,
                                                     const float* __restrict__ Pl,
                                                     const float* __restrict__ ELo,
                                                     const float* __restrict__ ELl,
                                                     const uint4* __restrict__ Kq,
                                                     float* __restrict__ wsacc) {
    __shared__ __align__(16) f16 U[2][4 * USTRIDE];
    __shared__ float CW[4][4];
    int t = threadIdx.x;
    int lane = t & 63, wv = t >> 6;
    int m16 = lane & 15, quad = lane >> 4;
    int w = blockIdx.x;           // 192 WGs
    int s = w >> 6;               // sinkhorn instance 0..2
    int ibase = (w & 63) * 4;     // 4 problems per WG
    int colbase = wv * 64;        // wave's 64-col slice
    int c_lane = colbase + quad * 16 + m16;  // this lane's epilogue column

    // B-fragments: K[k=kc*32+quad*8+j][c], register-resident; 4 col-tiles per wave
    uint4 bf[4][8];
    #pragma unroll
    for (int ct = 0; ct < 4; ct++)
        #pragma unroll
        for (int kc = 0; kc < 8; kc++)
            bf[ct][kc] = Kq[(kc * 4 + quad) * 256 + colbase + ct * 16 + m16];
    #pragma unroll
    for (int ct = 0; ct < 4; ct++)
        #pragma unroll
        for (int kc = 0; kc < 8; kc++) PIN_U4(bf[ct][kc]);

    // per-lane epilogue constants (own column only)
    const float* ELa_b = (s == 1 ? ELl : ELo);
    const float* ELb_b = (s == 2 ? ELo : ELl);
    float ef[4], eg[4], Ef[4], Eg[4];
    #pragma unroll
    for (int reg = 0; reg < 4; reg++) {
        int i = ibase + reg;
        ef[reg] = ELa_b[i * 256 + c_lane] + EPS * KSCALE_LN;
        eg[reg] = ELb_b[i * 256 + c_lane] + EPS * KSCALE_LN;
        Ef[reg] = __expf(ef[reg]);
        Eg[reg] = __expf(eg[reg]);
    }

    // init U[0] = 1.0 (f16 0x3C00): 4*272 halfs = 136 uint4
    if (t < 136)
        *(uint4*)&U[0][t * 8] =
            make_uint4(0x3C003C00u, 0x3C003C00u, 0x3C003C00u, 0x3C003C00u);
    __syncthreads();

    float zf[4], zg[4];
    for (int it = 0; it < 2 * SINK_ITERS; it++) {
        const f16* ub = &U[it & 1][0];
        f16* un = &U[(it + 1) & 1][0];
        f16x8 a[8];
        #pragma unroll
        for (int kc = 0; kc < 8; kc++)
            a[kc] = *(const f16x8*)&ub[(m16 & 3) * USTRIDE + kc * 32 + quad * 8];
        f32x4 accA[4] = {{0.f,0.f,0.f,0.f},{0.f,0.f,0.f,0.f},{0.f,0.f,0.f,0.f},{0.f,0.f,0.f,0.f}};
        f32x4 accB[4] = {{0.f,0.f,0.f,0.f},{0.f,0.f,0.f,0.f},{0.f,0.f,0.f,0.f},{0.f,0.f,0.f,0.f}};
        #pragma unroll
        for (int kc = 0; kc < 4; kc++)
            #pragma unroll
            for (int ct = 0; ct < 4; ct++)
                accA[ct] = __builtin_amdgcn_mfma_f32_16x16x32_f16(
                    a[kc], __builtin_bit_cast(f16x8, bf[ct][kc]), accA[ct], 0, 0, 0);
        #pragma unroll
        for (int kc = 4; kc < 8; kc++)
            #pragma unroll
            for (int ct = 0; ct < 4; ct++)
                accB[ct] = __builtin_amdgcn_mfma_f32_16x16x32_f16(
                    a[kc], __builtin_bit_cast(f16x8, bf[ct][kc]), accB[ct], 0, 0, 0);
        // quad q owns col-tile q (C rows are 4x duplicated across quads)
        float zsum[4];
        #pragma unroll
        for (int reg = 0; reg < 4; reg++) {
            float zA = sel4(quad, accA[0][reg], accA[1][reg], accA[2][reg], accA[3][reg]);
            float zB = sel4(quad, accB[0][reg], accB[1][reg], accB[2][reg], accB[3][reg]);
            zsum[reg] = zA + zB;
        }
        if (it == 2 * SINK_ITERS - 2) {
            #pragma unroll
            for (int reg = 0; reg < 4; reg++) zg[reg] = zsum[reg];
        }
        if (it == 2 * SINK_ITERS - 1) {
            #pragma unroll
            for (int reg = 0; reg < 4; reg++) zf[reg] = zsum[reg];
        }
        bool fstep = (it & 1);
        #pragma unroll
        for (int reg = 0; reg < 4; reg++) {
            float E = fstep ? Ef[reg] : Eg[reg];
            float p = __expf(-EPS * __logf(zsum[reg]));
            un[reg * USTRIDE + c_lane] = (f16)(E * p);
        }
        __syncthreads();
    }

    // cost epilogue: problem r=ibase+reg: sum_c Pa[c]*f[c] + Pb[c]*g[c]
    const float* PaB = (s == 1 ? Pl : Po);
    const float* PbB = (s == 2 ? Po : Pl);
    float cs[4];
    #pragma unroll
    for (int reg = 0; reg < 4; reg++) {
        int i = ibase + reg;
        float dfv = ef[reg] - EPS * __logf(zf[reg]);
        float dgv = eg[reg] - EPS * __logf(zg[reg]);
        cs[reg] = PaB[i * 256 + c_lane] * dfv + PbB[i * 256 + c_lane] * dgv;
    }
    #pragma unroll
    for (int reg = 0; reg < 4; reg++) cs[reg] = wave_red_sum(cs[reg]);
    if (lane == 0) {
        #pragma unroll
        for (int reg = 0; reg < 4; reg++) CW[wv][reg] = cs[reg];
    }
    __syncthreads();
    if (t == 0) {
        float v = 0.f;
        for (int w2 = 0; w2 < 4; w2++)
            v += CW[w2][0] + CW[w2][1] + CW[w2][2] + CW[w2][3];
        atomicAdd(&wsacc[s], v);
    }
}

// ---------------- finalize ----------------
__global__ void k_final(const float* __restrict__ wsacc, const float* __restrict__ lvr_p,
                        const float* __restrict__ lvt_p, float* __restrict__ out) {
    float recon = wsacc[3] * (1.f / (256.f * 4096.f));
    float ot0 = wsacc[0] * (1.f / 256.f);
    float ot1 = wsacc[1] * (1.f / 256.f);
    float ot2 = wsacc[2] * (1.f / 256.f);
    float topo = ot0 - 0.5f * ot1 - 0.5f * ot2;
    topo = topo > 0.f ? topo : 0.f;  // * TOPO_MULT (=1)
    float lvr = lvr_p[0], lvt = lvt_p[0];
    out[0] = 0.5f * __expf(-lvr) * recon + 0.5f * lvr +
             0.5f * __expf(-lvt) * topo + 0.5f * lvt;
    out[1] = recon;
    out[2] = topo;
}

extern "C" void kernel_launch(void* const* d_in, const int* in_sizes, int n_in,
                              void* d_out, int out_size, void* d_ws, size_t ws_size,
                              hipStream_t stream) {
    const float* xo = (const float*)d_in[0];
    const float* xr = (const float*)d_in[1];
    const float* z  = (const float*)d_in[2];
    const float* lsl = (const float*)d_in[3];
    const float* lvr = (const float*)d_in[4];
    const float* lvt = (const float*)d_in[5];
    float* out = (float*)d_out;
    float* ws = (float*)d_ws;

    // ws layout (floats)
    float* acc = ws;                    // [0..2] ot sums, [3] recon sum, [4] sigma_orig
    float* xh  = ws + 64;               // 256*4096 f16 = 524288 floats
    float* zh  = xh + 524288;           // 256*256 f16 = 32768 floats
    float* Do  = zh + 32768;
    float* Po  = Do + 65536;
    float* Pl  = Po + 65536;
    float* ELo = Pl + 65536;
    float* ELl = ELo + 65536;
    float* Kh  = ELl + 65536;           // 65536 f16 = 32768 floats
    float* part = Kh + 32768;           // 16*65536 (xh-gemm slabs)
    float* part2 = Po;                  // 4*65536 overlay: consumed by prep before it writes Po..ELl

    (void)hipMemsetAsync(acc, 0, 64, stream);
    k_pre<<<1024, 256, 0, stream>>>((const float4*)xo, (const float4*)xr, (const float4*)z,
                                    (f16x4*)xh, (f16x4*)zh, acc);
    k_gemm_f16<<<dim3(4, 4, 20), 256, 0, stream>>>((const uint4*)xh, (const uint4*)zh,
                                                   part, part2);
    k_reduce_do<<<256, 256, 0, stream>>>(part, Do);
    k_median<<<1, 1024, 0, stream>>>(Do, acc + 4);
    k_prep<<<256, 256, 0, stream>>>(Do, part2, acc, lsl, Po, Pl, ELo, ELl, (f16*)Kh);
    k_sinkhorn<<<192, 256, 0, stream>>>(Po, Pl, ELo, ELl, (const uint4*)Kh, acc);
    k_final<<<1, 1, 0, stream>>>(acc, lvr, lvt, out);
}